// Round 3
// baseline (859.800 us; speedup 1.0000x reference)
//
#include <hip/hip_runtime.h>
#include <hip/hip_bf16.h>

namespace {

constexpr int N_NODES = 100000;
constexpr int N_EDGES = 3200000;
constexpr int D = 16;
constexpr int H = 64;
constexpr int C = 10;
constexpr int L = 2;
constexpr int BLK = 256;
constexpr int NBN = (N_NODES + BLK - 1) / BLK;  // 391

constexpr int P = 128;                       // nodes per partition (c_local = col & 127)
constexpr int NP = (N_NODES + P - 1) / P;    // 782 partitions
constexpr int NBB = 128;                     // binning blocks
constexpr int EC = N_EDGES / NBB;            // 25000 edges per binning block

__global__ void k_zero(int* __restrict__ bin_cnt) {
  int i = threadIdx.x;
  for (; i < NP; i += 1024) bin_cnt[i] = 0;
}

// Per-block LDS histogram over bins; one global atomic per (block,bin) to reserve.
__global__ void k_bincount(const int* __restrict__ col, int* __restrict__ bin_cnt,
                           int* __restrict__ blk_start) {
  __shared__ int lh[NP];
  for (int i = threadIdx.x; i < NP; i += BLK) lh[i] = 0;
  __syncthreads();
  const int b = blockIdx.x;
  const int e0 = b * EC;
  for (int e = e0 + threadIdx.x; e < e0 + EC; e += BLK)
    atomicAdd(&lh[col[e] >> 7], 1);
  __syncthreads();
  for (int i = threadIdx.x; i < NP; i += BLK)
    blk_start[b * NP + i] = atomicAdd(&bin_cnt[i], lh[i]);
}

// Exclusive scan of bin_cnt[NP] -> bin_ptr (single block, NP=782 <= 1024).
__global__ void k_scanbins(const int* __restrict__ bin_cnt, int* __restrict__ bin_ptr) {
  __shared__ int s[1024];
  int t = threadIdx.x;
  int v = (t < NP) ? bin_cnt[t] : 0;
  s[t] = v;
  __syncthreads();
  for (int off = 1; off < 1024; off <<= 1) {
    int u = (t >= off) ? s[t - off] : 0;
    __syncthreads();
    s[t] += u;
    __syncthreads();
  }
  if (t < NP) bin_ptr[t] = s[t] - v;  // exclusive
  if (t == 0) bin_ptr[NP] = N_EDGES;
}

// Scatter records (row | c_local<<17, ew) into bin order using LDS cursors.
__global__ void k_binscatter(const int* __restrict__ row, const int* __restrict__ col,
                             const float* __restrict__ ew, const int* __restrict__ bin_ptr,
                             const int* __restrict__ blk_start, uint2* __restrict__ recs) {
  __shared__ int lcur[NP];
  const int b = blockIdx.x;
  for (int i = threadIdx.x; i < NP; i += BLK)
    lcur[i] = bin_ptr[i] + blk_start[b * NP + i];
  __syncthreads();
  const int e0 = b * EC;
  for (int e = e0 + threadIdx.x; e < e0 + EC; e += BLK) {
    int c = col[e];
    int bin = c >> 7;
    int pos = atomicAdd(&lcur[bin], 1);  // LDS atomic
    recs[pos] = make_uint2((unsigned)row[e] | ((unsigned)(c & (P - 1)) << 17),
                           __float_as_uint(ew[e]));
  }
}

// Per-partition degree via LDS accumulation (deg starts at 1 = self-loop), then dinv.
__global__ void k_degdinv(const uint2* __restrict__ recs, const int* __restrict__ bin_ptr,
                          float* __restrict__ dinv) {
  __shared__ float sdeg[P];
  const int b = blockIdx.x;
  if (threadIdx.x < P) sdeg[threadIdx.x] = 1.0f;
  __syncthreads();
  const int beg = bin_ptr[b], end = bin_ptr[b + 1];
  for (int p = beg + threadIdx.x; p < end; p += BLK) {
    uint2 r = recs[p];
    atomicAdd(&sdeg[r.x >> 17], __uint_as_float(r.y));
  }
  __syncthreads();
  int v = b * P + threadIdx.x;
  if (threadIdx.x < P && v < N_NODES) {
    float d = sdeg[threadIdx.x];
    dinv[v] = d > 0.f ? rsqrtf(fmaxf(d, 1e-30f)) : 0.f;
  }
}

// out[v,:] = h[v,:] @ W^T
__global__ void k_lin(const float* __restrict__ hin, const float* __restrict__ W,
                      float* __restrict__ out) {
  __shared__ float sW[D * D];
  sW[threadIdx.x] = W[threadIdx.x];
  __syncthreads();
  int v = blockIdx.x * BLK + threadIdx.x;
  if (v >= N_NODES) return;
  float hv[D];
  const float4* hp = reinterpret_cast<const float4*>(hin + (size_t)v * D);
#pragma unroll
  for (int c = 0; c < 4; ++c) {
    float4 t = hp[c];
    hv[4 * c + 0] = t.x; hv[4 * c + 1] = t.y;
    hv[4 * c + 2] = t.z; hv[4 * c + 3] = t.w;
  }
  float4* op = reinterpret_cast<float4*>(out + (size_t)v * D);
#pragma unroll
  for (int jc = 0; jc < 4; ++jc) {
    float o[4];
#pragma unroll
    for (int jj = 0; jj < 4; ++jj) {
      int j = jc * 4 + jj;
      float s = 0.f;
#pragma unroll
      for (int k = 0; k < D; ++k) s += hv[k] * sW[j * D + k];
      o[jj] = s;
    }
    op[jc] = make_float4(o[0], o[1], o[2], o[3]);
  }
}

// Per-partition aggregate (LDS accumulator, no global atomics) + fused
// nodeNN/tanh/LeakyReLU/LayerNorm epilogue. Block b owns nodes [b*P, b*P+P).
// 16 groups x 16 lanes; lane l owns feature l.
__global__ void k_agg(const uint2* __restrict__ recs, const int* __restrict__ bin_ptr,
                      const float* __restrict__ dinv, const float* __restrict__ out,
                      const float* __restrict__ Wn, const float* __restrict__ nb,
                      const float* __restrict__ cb, const float* __restrict__ lg,
                      const float* __restrict__ lb, float* __restrict__ h) {
  __shared__ float sacc[P * 17];  // padded stride 17 to spread banks
  __shared__ float sdinv[P];
  __shared__ float sWT[D * D];    // transposed: sWT[k*D + j] = Wn[j*D + k]
  __shared__ float snb[D], scb[D], slg[D], slb[D];
  const int b = blockIdx.x;
  const int base = b * P;
  const int tid = threadIdx.x;

  sWT[tid] = Wn[(tid & 15) * D + (tid >> 4)];
  if (tid < D) {
    snb[tid] = nb[tid]; scb[tid] = cb[tid];
    slg[tid] = lg[tid]; slb[tid] = lb[tid];
  }
  if (tid < P) {
    int v = base + tid;
    sdinv[tid] = (v < N_NODES) ? dinv[v] : 0.f;
  }
  __syncthreads();

  // init accumulator with self-loop term dinv[v]^2 * out[v,l]
  for (int i = tid; i < P * D; i += BLK) {
    int n = i >> 4, l = i & 15;
    int v = base + n;
    float d = sdinv[n];
    sacc[n * 17 + l] = (v < N_NODES) ? d * d * out[(size_t)v * D + l] : 0.f;
  }
  __syncthreads();

  const int g = tid >> 4;
  const int l = tid & 15;
  const int beg = bin_ptr[b], end = bin_ptr[b + 1];
  const int nrec = end - beg;
  const int nquad = nrec >> 2;

  for (int q = g; q < nquad; q += 16) {
    int p0 = beg + q * 4;
    uint2 r0 = recs[p0 + 0], r1 = recs[p0 + 1], r2 = recs[p0 + 2], r3 = recs[p0 + 3];
    int a0 = r0.x & 0x1FFFF, a1 = r1.x & 0x1FFFF, a2 = r2.x & 0x1FFFF, a3 = r3.x & 0x1FFFF;
    int c0 = r0.x >> 17, c1 = r1.x >> 17, c2 = r2.x >> 17, c3 = r3.x >> 17;
    float d0 = dinv[a0], d1 = dinv[a1], d2 = dinv[a2], d3 = dinv[a3];
    float v0 = out[(size_t)a0 * D + l], v1 = out[(size_t)a1 * D + l];
    float v2 = out[(size_t)a2 * D + l], v3 = out[(size_t)a3 * D + l];
    float n0 = d0 * __uint_as_float(r0.y) * sdinv[c0];
    float n1 = d1 * __uint_as_float(r1.y) * sdinv[c1];
    float n2 = d2 * __uint_as_float(r2.y) * sdinv[c2];
    float n3 = d3 * __uint_as_float(r3.y) * sdinv[c3];
    atomicAdd(&sacc[c0 * 17 + l], n0 * v0);
    atomicAdd(&sacc[c1 * 17 + l], n1 * v1);
    atomicAdd(&sacc[c2 * 17 + l], n2 * v2);
    atomicAdd(&sacc[c3 * 17 + l], n3 * v3);
  }
  if (g == 0) {  // tail (up to 3 records)
    for (int p = beg + nquad * 4; p < end; ++p) {
      uint2 r = recs[p];
      int a = r.x & 0x1FFFF, c = r.x >> 17;
      float nv = dinv[a] * __uint_as_float(r.y) * sdinv[c];
      atomicAdd(&sacc[c * 17 + l], nv * out[(size_t)a * D + l]);
    }
  }
  __syncthreads();

  // epilogue: nodeNN (tanh(W a + nb)) + conv_b + LeakyReLU + LayerNorm
  for (int nb0 = 0; nb0 < P / 16; ++nb0) {
    int n = nb0 * 16 + g;
    int v = base + n;
    float s = snb[l];
#pragma unroll
    for (int k = 0; k < D; ++k) s += sacc[n * 17 + k] * sWT[k * D + l];
    float u = tanhf(s) + scb[l];
    u = u > 0.f ? u : 0.2f * u;  // LeakyReLU(0.2)
    float mu = u;
#pragma unroll
    for (int m = 1; m < 16; m <<= 1) mu += __shfl_xor(mu, m, 64);
    mu *= (1.0f / D);
    float dd = u - mu;
    float var = dd * dd;
#pragma unroll
    for (int m = 1; m < 16; m <<= 1) var += __shfl_xor(var, m, 64);
    var *= (1.0f / D);
    float inv = rsqrtf(var + 1e-5f);
    if (v < N_NODES) h[(size_t)v * D + l] = dd * inv * slg[l] + slb[l];
  }
}

// out[v,:] = relu(h @ w1^T + b1) @ w2^T + b2
__global__ void k_cls(const float* __restrict__ h, const float* __restrict__ w1,
                      const float* __restrict__ b1, const float* __restrict__ w2,
                      const float* __restrict__ b2, float* __restrict__ out) {
  __shared__ float sw1[H * D];
  __shared__ float sb1[H];
  __shared__ float sw2[C * H];
  __shared__ float sb2[C];
  for (int i = threadIdx.x; i < H * D; i += BLK) sw1[i] = w1[i];
  for (int i = threadIdx.x; i < H; i += BLK) sb1[i] = b1[i];
  for (int i = threadIdx.x; i < C * H; i += BLK) sw2[i] = w2[i];
  for (int i = threadIdx.x; i < C; i += BLK) sb2[i] = b2[i];
  __syncthreads();
  int v = blockIdx.x * BLK + threadIdx.x;
  if (v >= N_NODES) return;
  float hv[D];
  const float4* hp = reinterpret_cast<const float4*>(h + (size_t)v * D);
#pragma unroll
  for (int c = 0; c < 4; ++c) {
    float4 t = hp[c];
    hv[4 * c + 0] = t.x; hv[4 * c + 1] = t.y;
    hv[4 * c + 2] = t.z; hv[4 * c + 3] = t.w;
  }
  float oc[C];
#pragma unroll
  for (int c = 0; c < C; ++c) oc[c] = sb2[c];
#pragma unroll
  for (int j = 0; j < H; ++j) {
    float s = sb1[j];
#pragma unroll
    for (int k = 0; k < D; ++k) s += hv[k] * sw1[j * D + k];
    s = fmaxf(s, 0.f);
#pragma unroll
    for (int c = 0; c < C; ++c) oc[c] += s * sw2[c * H + j];
  }
#pragma unroll
  for (int c = 0; c < C; ++c) out[(size_t)v * C + c] = oc[c];
}

inline char* align_up(char* p, size_t a) {
  return (char*)(((uintptr_t)p + a - 1) & ~(uintptr_t)(a - 1));
}

}  // namespace

extern "C" void kernel_launch(void* const* d_in, const int* in_sizes, int n_in,
                              void* d_out, int out_size, void* d_ws, size_t ws_size,
                              hipStream_t stream) {
  const float* x         = (const float*)d_in[0];
  const int*   edge_idx  = (const int*)d_in[1];   // [2, E]
  const float* edge_attr = (const float*)d_in[2];
  const float* lin_w  = (const float*)d_in[4];
  const float* conv_b = (const float*)d_in[5];
  const float* node_w = (const float*)d_in[6];
  const float* node_b = (const float*)d_in[7];
  const float* ln_g   = (const float*)d_in[8];
  const float* ln_b   = (const float*)d_in[9];
  const float* w1     = (const float*)d_in[10];
  const float* b1     = (const float*)d_in[11];
  const float* w2     = (const float*)d_in[12];
  const float* b2     = (const float*)d_in[13];
  float* out = (float*)d_out;

  const int* row = edge_idx;            // source
  const int* col = edge_idx + N_EDGES;  // target

  // workspace layout
  char* p = (char*)d_ws;
  int*   bin_cnt   = (int*)p;   p = align_up(p + sizeof(int) * NP, 256);
  int*   bin_ptr   = (int*)p;   p = align_up(p + sizeof(int) * (NP + 1), 256);
  int*   blk_start = (int*)p;   p = align_up(p + sizeof(int) * (size_t)NBB * NP, 256);
  float* dinv      = (float*)p; p = align_up(p + sizeof(float) * N_NODES, 256);
  uint2* recs      = (uint2*)p; p = align_up(p + sizeof(uint2) * (size_t)N_EDGES, 256);
  float* outb      = (float*)p; p = align_up(p + sizeof(float) * (size_t)N_NODES * D, 256);
  float* hbuf      = (float*)p; p = align_up(p + sizeof(float) * (size_t)N_NODES * D, 256);

  // ---- one-time atomic-free binning build ----
  k_zero<<<1, 1024, 0, stream>>>(bin_cnt);
  k_bincount<<<NBB, BLK, 0, stream>>>(col, bin_cnt, blk_start);
  k_scanbins<<<1, 1024, 0, stream>>>(bin_cnt, bin_ptr);
  k_binscatter<<<NBB, BLK, 0, stream>>>(row, col, edge_attr, bin_ptr, blk_start, recs);
  k_degdinv<<<NP, BLK, 0, stream>>>(recs, bin_ptr, dinv);

  // ---- layers ----
  for (int i = 0; i < L; ++i) {
    const float* hin = (i == 0) ? x : hbuf;
    k_lin<<<NBN, BLK, 0, stream>>>(hin, lin_w + i * D * D, outb);
    k_agg<<<NP, BLK, 0, stream>>>(recs, bin_ptr, dinv, outb,
                                  node_w + i * D * D, node_b + i * D, conv_b + i * D,
                                  ln_g + i * D, ln_b + i * D, hbuf);
  }
  k_cls<<<NBN, BLK, 0, stream>>>(hbuf, w1, b1, w2, b2, out);
}

// Round 4
// 776.680 us; speedup vs baseline: 1.1070x; 1.1070x over previous
//
#include <hip/hip_runtime.h>
#include <hip/hip_bf16.h>

namespace {

constexpr int N_NODES = 100000;
constexpr int N_EDGES = 3200000;
constexpr int D = 16;
constexpr int H = 64;
constexpr int C = 10;
constexpr int L = 2;
constexpr int BLK = 256;
constexpr int NBN = (N_NODES + BLK - 1) / BLK;  // 391

constexpr int P = 64;                        // nodes per partition (c_local = col & 63)
constexpr int NP = (N_NODES + P - 1) / P;    // 1563 partitions
constexpr int NBB = 128;                     // binning blocks
constexpr int EC = N_EDGES / NBB;            // 25000 edges per binning block

__global__ void k_zero(int* __restrict__ bin_cnt) {
  for (int i = threadIdx.x; i < NP; i += 1024) bin_cnt[i] = 0;
}

// Per-block LDS histogram over bins; one global atomic per (block,bin) to reserve.
__global__ void k_bincount(const int* __restrict__ col, int* __restrict__ bin_cnt,
                           int* __restrict__ blk_start) {
  __shared__ int lh[NP];
  for (int i = threadIdx.x; i < NP; i += BLK) lh[i] = 0;
  __syncthreads();
  const int b = blockIdx.x;
  const int e0 = b * EC;
  for (int e = e0 + threadIdx.x; e < e0 + EC; e += BLK)
    atomicAdd(&lh[col[e] >> 6], 1);
  __syncthreads();
  for (int i = threadIdx.x; i < NP; i += BLK)
    blk_start[b * NP + i] = atomicAdd(&bin_cnt[i], lh[i]);
}

// Exclusive scan of bin_cnt[NP] -> bin_ptr. Single block, 1024 thr, 2048-wide
// double-buffered Hillis-Steele.
__global__ void k_scanbins(const int* __restrict__ bin_cnt, int* __restrict__ bin_ptr) {
  __shared__ int s0[2048], s1[2048];
  const int t = threadIdx.x;
  int v0 = (t < NP) ? bin_cnt[t] : 0;
  int v1 = (t + 1024 < NP) ? bin_cnt[t + 1024] : 0;
  s0[t] = v0; s0[t + 1024] = v1;
  __syncthreads();
  int* cur = s0; int* nxt = s1;
  for (int off = 1; off < 2048; off <<= 1) {
    nxt[t] = cur[t] + (t >= off ? cur[t - off] : 0);
    int i1 = t + 1024;
    nxt[i1] = cur[i1] + (i1 >= off ? cur[i1 - off] : 0);
    __syncthreads();
    int* tmp = cur; cur = nxt; nxt = tmp;
  }
  if (t < NP) bin_ptr[t] = cur[t] - v0;
  if (t + 1024 < NP) bin_ptr[t + 1024] = cur[t + 1024] - v1;
  if (t == 0) bin_ptr[NP] = N_EDGES;
}

// Scatter records (row | c_local<<17, ew) into bin order using LDS cursors.
__global__ void k_binscatter(const int* __restrict__ row, const int* __restrict__ col,
                             const float* __restrict__ ew, const int* __restrict__ bin_ptr,
                             const int* __restrict__ blk_start, uint2* __restrict__ recs) {
  __shared__ int lcur[NP];
  const int b = blockIdx.x;
  for (int i = threadIdx.x; i < NP; i += BLK)
    lcur[i] = bin_ptr[i] + blk_start[b * NP + i];
  __syncthreads();
  const int e0 = b * EC;
  for (int e = e0 + threadIdx.x; e < e0 + EC; e += BLK) {
    int c = col[e];
    int pos = atomicAdd(&lcur[c >> 6], 1);  // LDS atomic
    recs[pos] = make_uint2((unsigned)row[e] | ((unsigned)(c & (P - 1)) << 17),
                           __float_as_uint(ew[e]));
  }
}

// Per-partition degree via LDS accumulation (deg starts at 1 = self-loop), then dinv.
__global__ void k_degdinv(const uint2* __restrict__ recs, const int* __restrict__ bin_ptr,
                          float* __restrict__ dinv) {
  __shared__ float sdeg[P];
  const int b = blockIdx.x;
  if (threadIdx.x < P) sdeg[threadIdx.x] = 1.0f;
  __syncthreads();
  const int beg = bin_ptr[b], end = bin_ptr[b + 1];
  for (int p = beg + threadIdx.x; p < end; p += BLK) {
    uint2 r = recs[p];
    atomicAdd(&sdeg[r.x >> 17], __uint_as_float(r.y));
  }
  __syncthreads();
  int v = b * P + threadIdx.x;
  if (threadIdx.x < P && v < N_NODES) {
    float d = sdeg[threadIdx.x];
    dinv[v] = d > 0.f ? rsqrtf(fmaxf(d, 1e-30f)) : 0.f;
  }
}

// outd[v,:] = dinv[v] * (h[v,:] @ W^T)   (dinv[row] folded into the message table)
__global__ void k_lin(const float* __restrict__ hin, const float* __restrict__ W,
                      const float* __restrict__ dinv, float* __restrict__ outd) {
  __shared__ float sW[D * D];
  sW[threadIdx.x] = W[threadIdx.x];
  __syncthreads();
  int v = blockIdx.x * BLK + threadIdx.x;
  if (v >= N_NODES) return;
  float hv[D];
  const float4* hp = reinterpret_cast<const float4*>(hin + (size_t)v * D);
#pragma unroll
  for (int c = 0; c < 4; ++c) {
    float4 t = hp[c];
    hv[4 * c + 0] = t.x; hv[4 * c + 1] = t.y;
    hv[4 * c + 2] = t.z; hv[4 * c + 3] = t.w;
  }
  float dv = dinv[v];
  float4* op = reinterpret_cast<float4*>(outd + (size_t)v * D);
#pragma unroll
  for (int jc = 0; jc < 4; ++jc) {
    float o[4];
#pragma unroll
    for (int jj = 0; jj < 4; ++jj) {
      int j = jc * 4 + jj;
      float s = 0.f;
#pragma unroll
      for (int k = 0; k < D; ++k) s += hv[k] * sW[j * D + k];
      o[jj] = s * dv;
    }
    op[jc] = make_float4(o[0], o[1], o[2], o[3]);
  }
}

// Per-partition aggregate + fused nodeNN/tanh/LeakyReLU/LayerNorm epilogue.
// agg[c] = dinv[c] * (outd[c] + sum_e ew_e * outd[row_e]); dinv[c] applied in epilogue.
// Block b owns nodes [b*P, b*P+P). 16 groups x 16 lanes; lane l owns feature l.
__global__ void k_agg(const uint2* __restrict__ recs, const int* __restrict__ bin_ptr,
                      const float* __restrict__ dinv, const float* __restrict__ outd,
                      const float* __restrict__ Wn, const float* __restrict__ nb,
                      const float* __restrict__ cb, const float* __restrict__ lg,
                      const float* __restrict__ lb, float* __restrict__ h) {
  __shared__ float sacc[P * 17];  // padded stride 17
  __shared__ float sdinv[P];
  __shared__ float sWT[D * D];    // sWT[k*D + j] = Wn[j*D + k]
  __shared__ float snb[D], scb[D], slg[D], slb[D];
  const int b = blockIdx.x;
  const int base = b * P;
  const int tid = threadIdx.x;

  sWT[tid] = Wn[(tid & 15) * D + (tid >> 4)];
  if (tid < D) {
    snb[tid] = nb[tid]; scb[tid] = cb[tid];
    slg[tid] = lg[tid]; slb[tid] = lb[tid];
  }
  if (tid < P) {
    int v = base + tid;
    sdinv[tid] = (v < N_NODES) ? dinv[v] : 0.f;
  }
  // init accumulator with outd[v,l] (self-loop; dinv[c] applied in epilogue)
  for (int i = tid; i < P * D; i += BLK) {
    int n = i >> 4, l = i & 15;
    int v = base + n;
    sacc[n * 17 + l] = (v < N_NODES) ? outd[(size_t)v * D + l] : 0.f;
  }
  __syncthreads();

  const int g = tid >> 4;
  const int l = tid & 15;
  const int beg = bin_ptr[b], end = bin_ptr[b + 1];
  const int nrec = end - beg;
  const int nch = nrec >> 3;  // chunks of 8 records

  for (int ch = g; ch < nch; ch += 16) {
    int p0 = beg + ch * 8;
    uint2 r[8];
#pragma unroll
    for (int i = 0; i < 8; ++i) r[i] = recs[p0 + i];
    float vv[8];
#pragma unroll
    for (int i = 0; i < 8; ++i)
      vv[i] = outd[(size_t)(r[i].x & 0x1FFFF) * D + l];
#pragma unroll
    for (int i = 0; i < 8; ++i)
      atomicAdd(&sacc[(r[i].x >> 17) * 17 + l], __uint_as_float(r[i].y) * vv[i]);
  }
  if (g == 0) {  // tail (<8 records)
    for (int p = beg + nch * 8; p < end; ++p) {
      uint2 r = recs[p];
      atomicAdd(&sacc[(r.x >> 17) * 17 + l],
                __uint_as_float(r.y) * outd[(size_t)(r.x & 0x1FFFF) * D + l]);
    }
  }
  __syncthreads();

  // epilogue: agg = sdinv[n]*sacc[n,:]; nodeNN tanh(W agg + nb) + cb, LeakyReLU, LN
#pragma unroll
  for (int nb0 = 0; nb0 < P / 16; ++nb0) {
    int n = nb0 * 16 + g;
    int v = base + n;
    float s = 0.f;
#pragma unroll
    for (int k = 0; k < D; ++k) s += sacc[n * 17 + k] * sWT[k * D + l];
    s = snb[l] + sdinv[n] * s;
    float u = tanhf(s) + scb[l];
    u = u > 0.f ? u : 0.2f * u;  // LeakyReLU(0.2)
    float mu = u;
#pragma unroll
    for (int m = 1; m < 16; m <<= 1) mu += __shfl_xor(mu, m, 64);
    mu *= (1.0f / D);
    float dd = u - mu;
    float var = dd * dd;
#pragma unroll
    for (int m = 1; m < 16; m <<= 1) var += __shfl_xor(var, m, 64);
    var *= (1.0f / D);
    float inv = rsqrtf(var + 1e-5f);
    if (v < N_NODES) h[(size_t)v * D + l] = dd * inv * slg[l] + slb[l];
  }
}

// out[v,:] = relu(h @ w1^T + b1) @ w2^T + b2
__global__ void k_cls(const float* __restrict__ h, const float* __restrict__ w1,
                      const float* __restrict__ b1, const float* __restrict__ w2,
                      const float* __restrict__ b2, float* __restrict__ out) {
  __shared__ float sw1[H * D];
  __shared__ float sb1[H];
  __shared__ float sw2[C * H];
  __shared__ float sb2[C];
  for (int i = threadIdx.x; i < H * D; i += BLK) sw1[i] = w1[i];
  for (int i = threadIdx.x; i < H; i += BLK) sb1[i] = b1[i];
  for (int i = threadIdx.x; i < C * H; i += BLK) sw2[i] = w2[i];
  for (int i = threadIdx.x; i < C; i += BLK) sb2[i] = b2[i];
  __syncthreads();
  int v = blockIdx.x * BLK + threadIdx.x;
  if (v >= N_NODES) return;
  float hv[D];
  const float4* hp = reinterpret_cast<const float4*>(h + (size_t)v * D);
#pragma unroll
  for (int c = 0; c < 4; ++c) {
    float4 t = hp[c];
    hv[4 * c + 0] = t.x; hv[4 * c + 1] = t.y;
    hv[4 * c + 2] = t.z; hv[4 * c + 3] = t.w;
  }
  float oc[C];
#pragma unroll
  for (int c = 0; c < C; ++c) oc[c] = sb2[c];
#pragma unroll
  for (int j = 0; j < H; ++j) {
    float s = sb1[j];
#pragma unroll
    for (int k = 0; k < D; ++k) s += hv[k] * sw1[j * D + k];
    s = fmaxf(s, 0.f);
#pragma unroll
    for (int c = 0; c < C; ++c) oc[c] += s * sw2[c * H + j];
  }
#pragma unroll
  for (int c = 0; c < C; ++c) out[(size_t)v * C + c] = oc[c];
}

inline char* align_up(char* p, size_t a) {
  return (char*)(((uintptr_t)p + a - 1) & ~(uintptr_t)(a - 1));
}

}  // namespace

extern "C" void kernel_launch(void* const* d_in, const int* in_sizes, int n_in,
                              void* d_out, int out_size, void* d_ws, size_t ws_size,
                              hipStream_t stream) {
  const float* x         = (const float*)d_in[0];
  const int*   edge_idx  = (const int*)d_in[1];   // [2, E]
  const float* edge_attr = (const float*)d_in[2];
  const float* lin_w  = (const float*)d_in[4];
  const float* conv_b = (const float*)d_in[5];
  const float* node_w = (const float*)d_in[6];
  const float* node_b = (const float*)d_in[7];
  const float* ln_g   = (const float*)d_in[8];
  const float* ln_b   = (const float*)d_in[9];
  const float* w1     = (const float*)d_in[10];
  const float* b1     = (const float*)d_in[11];
  const float* w2     = (const float*)d_in[12];
  const float* b2     = (const float*)d_in[13];
  float* out = (float*)d_out;

  const int* row = edge_idx;            // source
  const int* col = edge_idx + N_EDGES;  // target

  // workspace layout
  char* p = (char*)d_ws;
  int*   bin_cnt   = (int*)p;   p = align_up(p + sizeof(int) * NP, 256);
  int*   bin_ptr   = (int*)p;   p = align_up(p + sizeof(int) * (NP + 1), 256);
  int*   blk_start = (int*)p;   p = align_up(p + sizeof(int) * (size_t)NBB * NP, 256);
  float* dinv      = (float*)p; p = align_up(p + sizeof(float) * N_NODES, 256);
  uint2* recs      = (uint2*)p; p = align_up(p + sizeof(uint2) * (size_t)N_EDGES, 256);
  float* outb      = (float*)p; p = align_up(p + sizeof(float) * (size_t)N_NODES * D, 256);
  float* hbuf      = (float*)p; p = align_up(p + sizeof(float) * (size_t)N_NODES * D, 256);

  // ---- one-time atomic-free binning build ----
  k_zero<<<1, 1024, 0, stream>>>(bin_cnt);
  k_bincount<<<NBB, BLK, 0, stream>>>(col, bin_cnt, blk_start);
  k_scanbins<<<1, 1024, 0, stream>>>(bin_cnt, bin_ptr);
  k_binscatter<<<NBB, BLK, 0, stream>>>(row, col, edge_attr, bin_ptr, blk_start, recs);
  k_degdinv<<<NP, BLK, 0, stream>>>(recs, bin_ptr, dinv);

  // ---- layers ----
  for (int i = 0; i < L; ++i) {
    const float* hin = (i == 0) ? x : hbuf;
    k_lin<<<NBN, BLK, 0, stream>>>(hin, lin_w + i * D * D, dinv, outb);
    k_agg<<<NP, BLK, 0, stream>>>(recs, bin_ptr, dinv, outb,
                                  node_w + i * D * D, node_b + i * D, conv_b + i * D,
                                  ln_g + i * D, ln_b + i * D, hbuf);
  }
  k_cls<<<NBN, BLK, 0, stream>>>(hbuf, w1, b1, w2, b2, out);
}